// Round 14
// baseline (428.025 us; speedup 1.0000x reference)
//
#include <hip/hip_runtime.h>
#include <hip/hip_bf16.h>
#include <math.h>

#define DD     128
#define WROWS  32            // rows per wave
#define NWAVE  8
#define TPB    (NWAVE*64)    // 512 threads
#define TROWS  (NWAVE*WROWS) // 256 rows per tile
#define GRID_MLP 256
#define MAXG   8192

typedef __attribute__((ext_vector_type(8)))  short bf16x8;
typedef __attribute__((ext_vector_type(4)))  float f32x4;
typedef __attribute__((ext_vector_type(16))) float f32x16;

// static device scratch (rewritten every launch -> deterministic)
// layout: [L][T][ks][ft][lane][8]  (L=layer, T=hi/lo, ks=k-step of 16, ft=32-feature tile)
__device__ __align__(16) unsigned short g_wfrag[2*2*8*4*64*8]; // 128 KB
__device__ __align__(16) float g_b1p[DD];
__device__ float g_m, g_invZ;
__device__ float g_pm[MAXG], g_ps[MAXG];

__device__ __forceinline__ unsigned short f2b(float x){
    union { __hip_bfloat16 b; unsigned short u; } c;
    c.b = __float2bfloat16(x);
    return c.u;
}

// truncation-hi split: hi = upper 16 bits of f32, lo = RNE-bf16(x - hi).
__device__ __forceinline__ void split2(float x, unsigned short& h, unsigned short& l){
    unsigned int bx = __float_as_uint(x);
    float hf = __uint_as_float(bx & 0xFFFF0000u);
    h = (unsigned short)(bx >> 16);
    l = f2b(x - hf);
}

// ---- merged prep: blocks 0..31 split W1(:,0:128)/W2 into bf16 hi/lo A-frags;
//      block 32 folds u_rep half of layer1 into bias (fp32, parallel) ----
// A-frag: lane l holds A[m = ft*32 + (l&31)][k = ks*16 + (l>>5)*8 + r], r=0..7
__global__ __launch_bounds__(256)
void k_prep(const float* __restrict__ W1, const float* __restrict__ W2,
            const float* __restrict__ b1, const float* __restrict__ u)
{
    __shared__ float red[256];
    __shared__ float us[128];
    const int tid = threadIdx.x;

    if (blockIdx.x < 32){
        const int t    = blockIdx.x*256 + tid;           // 0..8191
        const int lane = t & 63;
        const int ft   = (t>>6) & 3;
        const int ks   = (t>>8) & 7;
        const int T    = (t>>11) & 1;                    // 0 = hi, 1 = lo
        const int L    = (t>>12) & 1;                    // 0 = layer1, 1 = layer2
        const int col  = ft*32 + (lane & 31);
        const int kb   = ks*16 + ((lane>>5) << 3);
        const float* src = L ? (W2 + (size_t)col*128 + kb) : (W1 + (size_t)col*256 + kb);
        unsigned short o[8];
        #pragma unroll
        for (int r = 0; r < 8; ++r){
            float x = src[r];
            unsigned short h, l;
            split2(x, h, l);
            o[r] = T ? l : h;
        }
        ushort4* dst = (ushort4*)&g_wfrag[(size_t)t * 8];
        dst[0] = *(ushort4*)&o[0];
        dst[1] = *(ushort4*)&o[4];
    } else {
        if (tid < 128) us[tid] = u[tid];
        __syncthreads();
        const int c = tid & 127, part = tid >> 7;
        const float* wr = W1 + (size_t)c*256 + 128 + part*64;
        float a = 0.f;
        #pragma unroll
        for (int j = 0; j < 64; ++j) a = fmaf(wr[j], us[part*64 + j], a);
        red[tid] = a;
        __syncthreads();
        if (part == 0) g_b1p[c] = red[c] + red[128 + c] + b1[c];
    }
}

__device__ __forceinline__ void load_xfrag(f32x4 (&xv)[16], const float* __restrict__ node1,
                                           int row, bool vrow, int hg)
{
    const float* xrow = node1 + (size_t)row * DD;
    #pragma unroll
    for (int ks = 0; ks < 8; ++ks){
        f32x4 a = {0.f,0.f,0.f,0.f}, b = {0.f,0.f,0.f,0.f};
        if (vrow){
            a = *(const f32x4*)(xrow + ks*16 + hg*8);
            b = *(const f32x4*)(xrow + ks*16 + hg*8 + 4);
        }
        xv[2*ks] = a; xv[2*ks+1] = b;
    }
}

__global__ __launch_bounds__(TPB, 2)
void k_mlp(const float* __restrict__ node1,
           const float* __restrict__ b2,
           const float* __restrict__ W3,
           float* __restrict__ out, int n)
{
    extern __shared__ __align__(16) unsigned short Wlds[];   // 131072 B = all W frags
    const int tid  = threadIdx.x;
    const int lane = tid & 63;
    const int w    = __builtin_amdgcn_readfirstlane(tid >> 6);
    const int hg   = lane >> 5;

    // ---- stage ALL W-fragments into LDS once (linear copy) ----
    {
        const f32x4* gs = (const f32x4*)g_wfrag;
        f32x4* ls = (f32x4*)Wlds;
        #pragma unroll
        for (int i = 0; i < 16; ++i) ls[i*TPB + tid] = gs[i*TPB + tid];
    }
    __syncthreads();   // the ONLY barrier; steady-state loop is barrier-free

    const bf16x8* WL = (const bf16x8*)Wlds;   // index: ((LT*8 + ks)*4 + mt)*64 + lane
    const int ntiles = (n + TROWS - 1) / TROWS;

    const int rbase = w*WROWS + (lane & 31);
    f32x4 xv[16];
    {
        const int row0 = blockIdx.x*TROWS + rbase;
        load_xfrag(xv, node1, row0, row0 < n, hg);
    }

    for (int t = blockIdx.x; t < ntiles; t += (int)gridDim.x){
        const int row  = t*TROWS + rbase;
        const bool vrow = row < n;

        // ---- split x -> B1 frags (xv freed after this) ----
        bf16x8 B1h[8], B1l[8];
        #pragma unroll
        for (int ks = 0; ks < 8; ++ks){
            union { ushort4 q[2]; bf16x8 v; } H, L;
            split2(xv[2*ks][0],   H.q[0].x, L.q[0].x);
            split2(xv[2*ks][1],   H.q[0].y, L.q[0].y);
            split2(xv[2*ks][2],   H.q[0].z, L.q[0].z);
            split2(xv[2*ks][3],   H.q[0].w, L.q[0].w);
            split2(xv[2*ks+1][0], H.q[1].x, L.q[1].x);
            split2(xv[2*ks+1][1], H.q[1].y, L.q[1].y);
            split2(xv[2*ks+1][2], H.q[1].z, L.q[1].z);
            split2(xv[2*ks+1][3], H.q[1].w, L.q[1].w);
            B1h[ks] = H.v; B1l[ks] = L.v;
        }

        // ---- layer 1: acc[mt][reg] ; feature m = mt*32 + qq*8 + hg*4 + j, row n = lane&31 ----
        f32x16 acc[4];
        #pragma unroll
        for (int mt = 0; mt < 4; ++mt){
            #pragma unroll
            for (int qq = 0; qq < 4; ++qq){
                const float4 bv = *(const float4*)&g_b1p[mt*32 + qq*8 + hg*4];
                acc[mt][qq*4+0] = bv.x; acc[mt][qq*4+1] = bv.y;
                acc[mt][qq*4+2] = bv.z; acc[mt][qq*4+3] = bv.w;
            }
        }
        #pragma unroll
        for (int ks = 0; ks < 8; ++ks){
            #pragma unroll
            for (int mt = 0; mt < 4; ++mt){
                const bf16x8 Ah = WL[((0*8 + ks)*4 + mt)*64 + lane];
                const bf16x8 Al = WL[((1*8 + ks)*4 + mt)*64 + lane];
                acc[mt] = __builtin_amdgcn_mfma_f32_32x32x16_bf16(Ah, B1h[ks], acc[mt], 0,0,0);
                acc[mt] = __builtin_amdgcn_mfma_f32_32x32x16_bf16(Ah, B1l[ks], acc[mt], 0,0,0);
                acc[mt] = __builtin_amdgcn_mfma_f32_32x32x16_bf16(Al, B1h[ks], acc[mt], 0,0,0);
            }
        }

        // ---- h1 -> B2 frags in-register via half-swap with lane^32 ----
        // lane holds offsets 4hg..4hg+3 of every 8-feature block; block b=2ks+hg is needed,
        // block 2ks+(1-hg) is sent. acc[b>>2][(b&3)*4+j] = offset 4hg+j of block b.
        bf16x8 B2h[8], B2l[8];
        #pragma unroll
        for (int ks = 0; ks < 8; ++ks){
            const int b0 = 2*ks, b1i = 2*ks + 1;
            ushort4 oh, ol, sh, sl;
            #pragma unroll
            for (int j = 0; j < 4; ++j){
                float a0 = fmaxf(acc[b0 >>2][(b0 &3)*4 + j], 0.f);   // block 2ks
                float a1 = fmaxf(acc[b1i>>2][(b1i&3)*4 + j], 0.f);   // block 2ks+1
                float vo = hg ? a1 : a0;    // my needed block 2ks+hg
                float vs = hg ? a0 : a1;    // block to send
                unsigned short h_, l_;
                split2(vo, h_, l_);
                ((unsigned short*)&oh)[j] = h_; ((unsigned short*)&ol)[j] = l_;
                split2(vs, h_, l_);
                ((unsigned short*)&sh)[j] = h_; ((unsigned short*)&sl)[j] = l_;
            }
            uint2 shu = *(uint2*)&sh, slu = *(uint2*)&sl;
            uint2 ohu = *(uint2*)&oh, olu = *(uint2*)&ol;
            uint2 rh, rl;
            rh.x = (unsigned)__shfl_xor((int)shu.x, 32);
            rh.y = (unsigned)__shfl_xor((int)shu.y, 32);
            rl.x = (unsigned)__shfl_xor((int)slu.x, 32);
            rl.y = (unsigned)__shfl_xor((int)slu.y, 32);
            union { unsigned int u[4]; bf16x8 v; } FH, FL;
            FH.u[0] = hg ? rh.x  : ohu.x;  FH.u[1] = hg ? rh.y  : ohu.y;
            FH.u[2] = hg ? ohu.x : rh.x;   FH.u[3] = hg ? ohu.y : rh.y;
            FL.u[0] = hg ? rl.x  : olu.x;  FL.u[1] = hg ? rl.y  : olu.y;
            FL.u[2] = hg ? olu.x : rl.x;   FL.u[3] = hg ? olu.y : rl.y;
            B2h[ks] = FH.v; B2l[ks] = FL.v;
        }

        // ---- prefetch next tile's x while layer 2 computes (reuses xv regs) ----
        {
            const int tn = t + (int)gridDim.x;
            if (tn < ntiles){
                const int rown = tn*TROWS + rbase;
                load_xfrag(xv, node1, rown, rown < n, hg);
            }
        }

        // ---- layer 2 ----
        #pragma unroll
        for (int mt = 0; mt < 4; ++mt){
            #pragma unroll
            for (int qq = 0; qq < 4; ++qq){
                const float4 bv = *(const float4*)&b2[mt*32 + qq*8 + hg*4];
                acc[mt][qq*4+0] = bv.x; acc[mt][qq*4+1] = bv.y;
                acc[mt][qq*4+2] = bv.z; acc[mt][qq*4+3] = bv.w;
            }
        }
        #pragma unroll
        for (int ks = 0; ks < 8; ++ks){
            #pragma unroll
            for (int mt = 0; mt < 4; ++mt){
                const bf16x8 Ah = WL[((2*8 + ks)*4 + mt)*64 + lane];
                const bf16x8 Al = WL[((3*8 + ks)*4 + mt)*64 + lane];
                acc[mt] = __builtin_amdgcn_mfma_f32_32x32x16_bf16(Ah, B2h[ks], acc[mt], 0,0,0);
                acc[mt] = __builtin_amdgcn_mfma_f32_32x32x16_bf16(Ah, B2l[ks], acc[mt], 0,0,0);
                acc[mt] = __builtin_amdgcn_mfma_f32_32x32x16_bf16(Al, B2h[ks], acc[mt], 0,0,0);
            }
        }

        // ---- layer 3: lane partial over its 64 features, + half-sum with lane^32 ----
        float p = 0.f;
        #pragma unroll
        for (int mt = 0; mt < 4; ++mt){
            #pragma unroll
            for (int qq = 0; qq < 4; ++qq){
                const float4 wv = *(const float4*)&W3[mt*32 + qq*8 + hg*4];
                p = fmaf(fmaxf(acc[mt][qq*4+0], 0.f), wv.x, p);
                p = fmaf(fmaxf(acc[mt][qq*4+1], 0.f), wv.y, p);
                p = fmaf(fmaxf(acc[mt][qq*4+2], 0.f), wv.z, p);
                p = fmaf(fmaxf(acc[mt][qq*4+3], 0.f), wv.w, p);
            }
        }
        p += __shfl_xor(p, 32);
        const float s = p;
        if (vrow && lane < 32) out[row] = s;

        // per-wave softmax stats over its 32 rows
        float m = (vrow && lane < 32) ? s : -3.0e38f;
        #pragma unroll
        for (int off = 32; off > 0; off >>= 1) m = fmaxf(m, __shfl_xor(m, off));
        float e = (vrow && lane < 32) ? expf(s - m) : 0.f;
        #pragma unroll
        for (int off = 32; off > 0; off >>= 1) e += __shfl_xor(e, off);
        if (lane == 0){ g_pm[t*NWAVE + w] = m; g_ps[t*NWAVE + w] = e; }
    }
}

__global__ __launch_bounds__(1024)
void k_combine(int ng)
{
    __shared__ float red[17];
    const int tid = threadIdx.x, lane = tid & 63, wv = tid >> 6;

    float m = -3.0e38f;
    for (int i = tid; i < ng; i += 1024) m = fmaxf(m, g_pm[i]);
    #pragma unroll
    for (int off = 32; off > 0; off >>= 1) m = fmaxf(m, __shfl_xor(m, off));
    if (lane == 0) red[wv] = m;
    __syncthreads();
    if (tid < 64){
        float v = (lane < 16) ? red[lane] : -3.0e38f;
        #pragma unroll
        for (int off = 32; off > 0; off >>= 1) v = fmaxf(v, __shfl_xor(v, off));
        if (lane == 0) red[16] = v;
    }
    __syncthreads();
    m = red[16];

    float z = 0.f;
    for (int i = tid; i < ng; i += 1024) z += g_ps[i] * expf(g_pm[i] - m);
    #pragma unroll
    for (int off = 32; off > 0; off >>= 1) z += __shfl_xor(z, off);
    __syncthreads();
    if (lane == 0) red[wv] = z;
    __syncthreads();
    if (tid < 64){
        float v = (lane < 16) ? red[lane] : 0.f;
        #pragma unroll
        for (int off = 32; off > 0; off >>= 1) v += __shfl_xor(v, off);
        if (lane == 0){ g_m = m; g_invZ = 1.0f / v; }
    }
}

__global__ __launch_bounds__(256)
void k_norm(float* __restrict__ s, int n)
{
    const int i = blockIdx.x * 256 + threadIdx.x;
    const float m = g_m, r = g_invZ;
    const int n4 = n >> 2;
    if (i < n4){
        float4 v = reinterpret_cast<float4*>(s)[i];
        v.x = expf(v.x - m) * r;
        v.y = expf(v.y - m) * r;
        v.z = expf(v.z - m) * r;
        v.w = expf(v.w - m) * r;
        reinterpret_cast<float4*>(s)[i] = v;
    }
    const int rem = n - (n4 << 2);
    if (i < rem){
        int t = (n4 << 2) + i;
        s[t] = expf(s[t] - m) * r;
    }
}

extern "C" void kernel_launch(void* const* d_in, const int* in_sizes, int n_in,
                              void* d_out, int out_size, void* d_ws, size_t ws_size,
                              hipStream_t stream)
{
    const float* node1 = (const float*)d_in[0];
    const float* urep  = (const float*)d_in[1];
    const float* W1    = (const float*)d_in[3];
    const float* b1    = (const float*)d_in[4];
    const float* W2    = (const float*)d_in[5];
    const float* b2    = (const float*)d_in[6];
    const float* W3    = (const float*)d_in[7];
    float* out = (float*)d_out;

    const int n      = in_sizes[0] / DD;              // 200000
    const int ntiles = (n + TROWS - 1) / TROWS;       // 782
    const int ng     = ntiles * NWAVE;                // 6256

    // allow 128 KB dynamic LDS (idempotent, not a stream op)
    hipFuncSetAttribute((const void*)k_mlp,
                        hipFuncAttributeMaxDynamicSharedMemorySize, 131072);

    k_prep<<<dim3(33), dim3(256), 0, stream>>>(W1, W2, b1, urep);
    k_mlp<<<dim3(GRID_MLP), dim3(TPB), 131072, stream>>>(node1, b2, W3, out, n);
    k_combine<<<dim3(1), dim3(1024), 0, stream>>>(ng);

    const int n4  = n >> 2;
    const int nb3 = (n4 + 255) / 256 > 0 ? (n4 + 255) / 256 : 1;
    k_norm<<<dim3(nb3), dim3(256), 0, stream>>>(out, n);
}

// Round 15
// 385.521 us; speedup vs baseline: 1.1103x; 1.1103x over previous
//
#include <hip/hip_runtime.h>
#include <hip/hip_bf16.h>
#include <math.h>

#define DD     128
#define WROWS  32            // rows per wave
#define NWAVE  8
#define TPB    (NWAVE*64)    // 512 threads
#define TROWS  (NWAVE*WROWS) // 256 rows per tile
#define GRID_MLP 256
#define MAXG   8192

typedef __attribute__((ext_vector_type(8)))  short bf16x8;
typedef __attribute__((ext_vector_type(4)))  float f32x4;
typedef __attribute__((ext_vector_type(16))) float f32x16;

// static device scratch (rewritten every launch -> deterministic)
// layout: [L][T][ks][ft][lane][8]  (L=layer, T=hi/lo, ks=k-step of 16, ft=32-feature tile)
__device__ __align__(16) unsigned short g_wfrag[2*2*8*4*64*8]; // 128 KB
__device__ __align__(16) float g_b1p[DD];
__device__ float g_m, g_invZ;
__device__ float g_pm[MAXG], g_ps[MAXG];

__device__ __forceinline__ unsigned short f2b(float x){
    union { __hip_bfloat16 b; unsigned short u; } c;
    c.b = __float2bfloat16(x);
    return c.u;
}

// truncation-hi split: hi = upper 16 bits of f32, lo = RNE-bf16(x - hi).
__device__ __forceinline__ void split2(float x, unsigned short& h, unsigned short& l){
    unsigned int bx = __float_as_uint(x);
    float hf = __uint_as_float(bx & 0xFFFF0000u);
    h = (unsigned short)(bx >> 16);
    l = f2b(x - hf);
}

// ---- merged prep: blocks 0..31 split W1(:,0:128)/W2 into bf16 hi/lo A-frags;
//      block 32 folds u_rep half of layer1 into bias (fp32, parallel) ----
// A-frag: lane l holds A[m = ft*32 + (l&31)][k = ks*16 + (l>>5)*8 + r], r=0..7
__global__ __launch_bounds__(256)
void k_prep(const float* __restrict__ W1, const float* __restrict__ W2,
            const float* __restrict__ b1, const float* __restrict__ u)
{
    __shared__ float red[256];
    __shared__ float us[128];
    const int tid = threadIdx.x;

    if (blockIdx.x < 32){
        const int t    = blockIdx.x*256 + tid;           // 0..8191
        const int lane = t & 63;
        const int ft   = (t>>6) & 3;
        const int ks   = (t>>8) & 7;
        const int T    = (t>>11) & 1;                    // 0 = hi, 1 = lo
        const int L    = (t>>12) & 1;                    // 0 = layer1, 1 = layer2
        const int col  = ft*32 + (lane & 31);
        const int kb   = ks*16 + ((lane>>5) << 3);
        const float* src = L ? (W2 + (size_t)col*128 + kb) : (W1 + (size_t)col*256 + kb);
        unsigned short o[8];
        #pragma unroll
        for (int r = 0; r < 8; ++r){
            float x = src[r];
            unsigned short h, l;
            split2(x, h, l);
            o[r] = T ? l : h;
        }
        ushort4* dst = (ushort4*)&g_wfrag[(size_t)t * 8];
        dst[0] = *(ushort4*)&o[0];
        dst[1] = *(ushort4*)&o[4];
    } else {
        if (tid < 128) us[tid] = u[tid];
        __syncthreads();
        const int c = tid & 127, part = tid >> 7;
        const float* wr = W1 + (size_t)c*256 + 128 + part*64;
        float a = 0.f;
        #pragma unroll
        for (int j = 0; j < 64; ++j) a = fmaf(wr[j], us[part*64 + j], a);
        red[tid] = a;
        __syncthreads();
        if (part == 0) g_b1p[c] = red[c] + red[128 + c] + b1[c];
    }
}

__global__ __launch_bounds__(TPB, 2)
void k_mlp(const float* __restrict__ node1,
           const float* __restrict__ b2,
           const float* __restrict__ W3,
           float* __restrict__ out, int n)
{
    extern __shared__ __align__(16) unsigned short Wlds[];   // 131072 B = all W frags
    const int tid  = threadIdx.x;
    const int lane = tid & 63;
    const int w    = __builtin_amdgcn_readfirstlane(tid >> 6);
    const int hg   = lane >> 5;

    // ---- stage ALL W-fragments into LDS once (linear copy) ----
    {
        const f32x4* gs = (const f32x4*)g_wfrag;
        f32x4* ls = (f32x4*)Wlds;
        #pragma unroll
        for (int i = 0; i < 16; ++i) ls[i*TPB + tid] = gs[i*TPB + tid];
    }
    __syncthreads();   // the ONLY barrier; steady-state loop is barrier-free

    const bf16x8* WL = (const bf16x8*)Wlds;   // index: ((LT*8 + ks)*4 + mt)*64 + lane
    const int ntiles = (n + TROWS - 1) / TROWS;
    const int rbase  = w*WROWS + (lane & 31);

    for (int t = blockIdx.x; t < ntiles; t += (int)gridDim.x){
        const int row   = t*TROWS + rbase;
        const bool vrow = row < n;
        const float* xrow = node1 + (size_t)row * DD;

        // ---- load + split x -> B1 frags, inline per ks (no persistent xv array) ----
        bf16x8 B1h[8], B1l[8];
        #pragma unroll
        for (int ks = 0; ks < 8; ++ks){
            f32x4 a = {0.f,0.f,0.f,0.f}, b = {0.f,0.f,0.f,0.f};
            if (vrow){
                a = *(const f32x4*)(xrow + ks*16 + hg*8);
                b = *(const f32x4*)(xrow + ks*16 + hg*8 + 4);
            }
            union { ushort4 q[2]; bf16x8 v; } H, L;
            split2(a[0], H.q[0].x, L.q[0].x);
            split2(a[1], H.q[0].y, L.q[0].y);
            split2(a[2], H.q[0].z, L.q[0].z);
            split2(a[3], H.q[0].w, L.q[0].w);
            split2(b[0], H.q[1].x, L.q[1].x);
            split2(b[1], H.q[1].y, L.q[1].y);
            split2(b[2], H.q[1].z, L.q[1].z);
            split2(b[3], H.q[1].w, L.q[1].w);
            B1h[ks] = H.v; B1l[ks] = L.v;
        }

        // ---- layer 1: acc[mt][reg]; feature m = mt*32 + qq*8 + hg*4 + j, row = lane&31 ----
        f32x16 acc[4];
        #pragma unroll
        for (int mt = 0; mt < 4; ++mt){
            #pragma unroll
            for (int qq = 0; qq < 4; ++qq){
                const float4 bv = *(const float4*)&g_b1p[mt*32 + qq*8 + hg*4];
                acc[mt][qq*4+0] = bv.x; acc[mt][qq*4+1] = bv.y;
                acc[mt][qq*4+2] = bv.z; acc[mt][qq*4+3] = bv.w;
            }
        }
        #pragma unroll
        for (int ks = 0; ks < 8; ++ks){
            #pragma unroll
            for (int mt = 0; mt < 4; ++mt){
                const bf16x8 Ah = WL[((0*8 + ks)*4 + mt)*64 + lane];
                const bf16x8 Al = WL[((1*8 + ks)*4 + mt)*64 + lane];
                acc[mt] = __builtin_amdgcn_mfma_f32_32x32x16_bf16(Ah, B1h[ks], acc[mt], 0,0,0);
                acc[mt] = __builtin_amdgcn_mfma_f32_32x32x16_bf16(Ah, B1l[ks], acc[mt], 0,0,0);
                acc[mt] = __builtin_amdgcn_mfma_f32_32x32x16_bf16(Al, B1h[ks], acc[mt], 0,0,0);
            }
        }

        // ---- h1 -> B2 frags in-register via half-swap with lane^32 (R14-verified) ----
        bf16x8 B2h[8], B2l[8];
        #pragma unroll
        for (int ks = 0; ks < 8; ++ks){
            const int b0 = 2*ks, b1i = 2*ks + 1;
            ushort4 oh, ol, sh, sl;
            #pragma unroll
            for (int j = 0; j < 4; ++j){
                float a0 = fmaxf(acc[b0 >>2][(b0 &3)*4 + j], 0.f);   // block 2ks
                float a1 = fmaxf(acc[b1i>>2][(b1i&3)*4 + j], 0.f);   // block 2ks+1
                float vo = hg ? a1 : a0;    // my needed block 2ks+hg
                float vs = hg ? a0 : a1;    // block to send
                unsigned short h_, l_;
                split2(vo, h_, l_);
                ((unsigned short*)&oh)[j] = h_; ((unsigned short*)&ol)[j] = l_;
                split2(vs, h_, l_);
                ((unsigned short*)&sh)[j] = h_; ((unsigned short*)&sl)[j] = l_;
            }
            uint2 shu = *(uint2*)&sh, slu = *(uint2*)&sl;
            uint2 ohu = *(uint2*)&oh, olu = *(uint2*)&ol;
            uint2 rh, rl;
            rh.x = (unsigned)__shfl_xor((int)shu.x, 32);
            rh.y = (unsigned)__shfl_xor((int)shu.y, 32);
            rl.x = (unsigned)__shfl_xor((int)slu.x, 32);
            rl.y = (unsigned)__shfl_xor((int)slu.y, 32);
            union { unsigned int u[4]; bf16x8 v; } FH, FL;
            FH.u[0] = hg ? rh.x  : ohu.x;  FH.u[1] = hg ? rh.y  : ohu.y;
            FH.u[2] = hg ? ohu.x : rh.x;   FH.u[3] = hg ? ohu.y : rh.y;
            FL.u[0] = hg ? rl.x  : olu.x;  FL.u[1] = hg ? rl.y  : olu.y;
            FL.u[2] = hg ? olu.x : rl.x;   FL.u[3] = hg ? olu.y : rl.y;
            B2h[ks] = FH.v; B2l[ks] = FL.v;
        }

        // ---- layer 2 ----
        #pragma unroll
        for (int mt = 0; mt < 4; ++mt){
            #pragma unroll
            for (int qq = 0; qq < 4; ++qq){
                const float4 bv = *(const float4*)&b2[mt*32 + qq*8 + hg*4];
                acc[mt][qq*4+0] = bv.x; acc[mt][qq*4+1] = bv.y;
                acc[mt][qq*4+2] = bv.z; acc[mt][qq*4+3] = bv.w;
            }
        }
        #pragma unroll
        for (int ks = 0; ks < 8; ++ks){
            #pragma unroll
            for (int mt = 0; mt < 4; ++mt){
                const bf16x8 Ah = WL[((2*8 + ks)*4 + mt)*64 + lane];
                const bf16x8 Al = WL[((3*8 + ks)*4 + mt)*64 + lane];
                acc[mt] = __builtin_amdgcn_mfma_f32_32x32x16_bf16(Ah, B2h[ks], acc[mt], 0,0,0);
                acc[mt] = __builtin_amdgcn_mfma_f32_32x32x16_bf16(Ah, B2l[ks], acc[mt], 0,0,0);
                acc[mt] = __builtin_amdgcn_mfma_f32_32x32x16_bf16(Al, B2h[ks], acc[mt], 0,0,0);
            }
        }

        // ---- layer 3: lane partial over its 64 features, + half-sum with lane^32 ----
        float p = 0.f;
        #pragma unroll
        for (int mt = 0; mt < 4; ++mt){
            #pragma unroll
            for (int qq = 0; qq < 4; ++qq){
                const float4 wv = *(const float4*)&W3[mt*32 + qq*8 + hg*4];
                p = fmaf(fmaxf(acc[mt][qq*4+0], 0.f), wv.x, p);
                p = fmaf(fmaxf(acc[mt][qq*4+1], 0.f), wv.y, p);
                p = fmaf(fmaxf(acc[mt][qq*4+2], 0.f), wv.z, p);
                p = fmaf(fmaxf(acc[mt][qq*4+3], 0.f), wv.w, p);
            }
        }
        p += __shfl_xor(p, 32);
        const float s = p;
        if (vrow && lane < 32) out[row] = s;

        // per-wave softmax stats over its 32 rows
        float m = (vrow && lane < 32) ? s : -3.0e38f;
        #pragma unroll
        for (int off = 32; off > 0; off >>= 1) m = fmaxf(m, __shfl_xor(m, off));
        float e = (vrow && lane < 32) ? expf(s - m) : 0.f;
        #pragma unroll
        for (int off = 32; off > 0; off >>= 1) e += __shfl_xor(e, off);
        if (lane == 0){ g_pm[t*NWAVE + w] = m; g_ps[t*NWAVE + w] = e; }
    }
}

__global__ __launch_bounds__(1024)
void k_combine(int ng)
{
    __shared__ float red[17];
    const int tid = threadIdx.x, lane = tid & 63, wv = tid >> 6;

    float m = -3.0e38f;
    for (int i = tid; i < ng; i += 1024) m = fmaxf(m, g_pm[i]);
    #pragma unroll
    for (int off = 32; off > 0; off >>= 1) m = fmaxf(m, __shfl_xor(m, off));
    if (lane == 0) red[wv] = m;
    __syncthreads();
    if (tid < 64){
        float v = (lane < 16) ? red[lane] : -3.0e38f;
        #pragma unroll
        for (int off = 32; off > 0; off >>= 1) v = fmaxf(v, __shfl_xor(v, off));
        if (lane == 0) red[16] = v;
    }
    __syncthreads();
    m = red[16];

    float z = 0.f;
    for (int i = tid; i < ng; i += 1024) z += g_ps[i] * expf(g_pm[i] - m);
    #pragma unroll
    for (int off = 32; off > 0; off >>= 1) z += __shfl_xor(z, off);
    __syncthreads();
    if (lane == 0) red[wv] = z;
    __syncthreads();
    if (tid < 64){
        float v = (lane < 16) ? red[lane] : 0.f;
        #pragma unroll
        for (int off = 32; off > 0; off >>= 1) v += __shfl_xor(v, off);
        if (lane == 0){ g_m = m; g_invZ = 1.0f / v; }
    }
}

__global__ __launch_bounds__(256)
void k_norm(float* __restrict__ s, int n)
{
    const int i = blockIdx.x * 256 + threadIdx.x;
    const float m = g_m, r = g_invZ;
    const int n4 = n >> 2;
    if (i < n4){
        float4 v = reinterpret_cast<float4*>(s)[i];
        v.x = expf(v.x - m) * r;
        v.y = expf(v.y - m) * r;
        v.z = expf(v.z - m) * r;
        v.w = expf(v.w - m) * r;
        reinterpret_cast<float4*>(s)[i] = v;
    }
    const int rem = n - (n4 << 2);
    if (i < rem){
        int t = (n4 << 2) + i;
        s[t] = expf(s[t] - m) * r;
    }
}

extern "C" void kernel_launch(void* const* d_in, const int* in_sizes, int n_in,
                              void* d_out, int out_size, void* d_ws, size_t ws_size,
                              hipStream_t stream)
{
    const float* node1 = (const float*)d_in[0];
    const float* urep  = (const float*)d_in[1];
    const float* W1    = (const float*)d_in[3];
    const float* b1    = (const float*)d_in[4];
    const float* W2    = (const float*)d_in[5];
    const float* b2    = (const float*)d_in[6];
    const float* W3    = (const float*)d_in[7];
    float* out = (float*)d_out;

    const int n      = in_sizes[0] / DD;              // 200000
    const int ntiles = (n + TROWS - 1) / TROWS;       // 782
    const int ng     = ntiles * NWAVE;                // 6256

    // allow 128 KB dynamic LDS (idempotent, not a stream op)
    hipFuncSetAttribute((const void*)k_mlp,
                        hipFuncAttributeMaxDynamicSharedMemorySize, 131072);

    k_prep<<<dim3(33), dim3(256), 0, stream>>>(W1, W2, b1, urep);
    k_mlp<<<dim3(GRID_MLP), dim3(TPB), 131072, stream>>>(node1, b2, W3, out, n);
    k_combine<<<dim3(1), dim3(1024), 0, stream>>>(ng);

    const int n4  = n >> 2;
    const int nb3 = (n4 + 255) / 256 > 0 ? (n4 + 255) / 256 : 1;
    k_norm<<<dim3(nb3), dim3(256), 0, stream>>>(out, n);
}

// Round 16
// 59.280 us; speedup vs baseline: 7.2204x; 6.5034x over previous
//
#include <hip/hip_runtime.h>
#include <hip/hip_bf16.h>
#include <math.h>

#define DD     128
#define BROWS  64          // rows per block
#define NWAVE  8
#define TPB    (NWAVE*64)  // 512 threads
#define XSTR   136         // bf16 elems per LDS row (272B: 16B-aligned, 2-way-free banks for 16-row frags)
#define MAXG   8192

typedef __attribute__((ext_vector_type(8)))  short bf16x8;
typedef __attribute__((ext_vector_type(4)))  float f32x4;

// static device scratch (rewritten every launch -> deterministic)
// 16x16x32 A-frag layout: [L][T][ks4][ft8][lane][8]
// lane l holds A[m = ft*16 + (l&15)][k = ks*32 + (l>>4)*8 + r], r=0..7
__device__ __align__(16) unsigned short g_wfrag[2*2*4*8*64*8]; // 128 KB
__device__ __align__(16) float g_b1p[DD];
__device__ float g_m, g_invZ;
__device__ float g_pm[MAXG], g_ps[MAXG];

__device__ __forceinline__ unsigned short f2b(float x){
    union { __hip_bfloat16 b; unsigned short u; } c;
    c.b = __float2bfloat16(x);
    return c.u;
}

// truncation-hi split: hi = upper 16 bits of f32, lo = RNE-bf16(x - hi).
__device__ __forceinline__ void split2(float x, unsigned short& h, unsigned short& l){
    unsigned int bx = __float_as_uint(x);
    float hf = __uint_as_float(bx & 0xFFFF0000u);
    h = (unsigned short)(bx >> 16);
    l = f2b(x - hf);
}

// ---- merged prep: blocks 0..31 build 16x16x32 A-frags (hi/lo); block 32 builds b1p ----
__global__ __launch_bounds__(256)
void k_prep(const float* __restrict__ W1, const float* __restrict__ W2,
            const float* __restrict__ b1, const float* __restrict__ u)
{
    __shared__ float red[256];
    __shared__ float us[128];
    const int tid = threadIdx.x;

    if (blockIdx.x < 32){
        const int t    = blockIdx.x*256 + tid;           // 0..8191
        const int lane = t & 63;
        const int ft   = (t>>6) & 7;                     // 8 tiles of 16 features
        const int ks   = (t>>9) & 3;                     // 4 k-steps of 32
        const int T    = (t>>11) & 1;                    // 0 = hi, 1 = lo
        const int L    = (t>>12) & 1;                    // 0 = layer1, 1 = layer2
        const int col  = ft*16 + (lane & 15);
        const int kb   = ks*32 + ((lane>>4) << 3);
        const float* src = L ? (W2 + (size_t)col*128 + kb) : (W1 + (size_t)col*256 + kb);
        unsigned short o[8];
        #pragma unroll
        for (int r = 0; r < 8; ++r){
            float x = src[r];
            unsigned short h, l;
            split2(x, h, l);
            o[r] = T ? l : h;
        }
        ushort4* dst = (ushort4*)&g_wfrag[(size_t)t * 8];
        dst[0] = *(ushort4*)&o[0];
        dst[1] = *(ushort4*)&o[4];
    } else {
        if (tid < 128) us[tid] = u[tid];
        __syncthreads();
        const int c = tid & 127, part = tid >> 7;
        const float* wr = W1 + (size_t)c*256 + 128 + part*64;
        float a = 0.f;
        #pragma unroll
        for (int j = 0; j < 64; ++j) a = fmaf(wr[j], us[part*64 + j], a);
        red[tid] = a;
        __syncthreads();
        if (part == 0) g_b1p[c] = red[c] + red[128 + c] + b1[c];
    }
}

// One layer: wave w computes features [16w,16w+16) x all 64 rows.
// A resident (8 frags, 32 VGPR); B streamed from LDS as single ds_read_b128.
__device__ __forceinline__ void layer_compute(
    const bf16x8 (&Ah)[4], const bf16x8 (&Al)[4],
    const unsigned short* __restrict__ Xh,
    const unsigned short* __restrict__ Xl,
    float4 bv, f32x4 (&acc)[4], int lane)
{
    const int r16 = lane & 15;
    const int hg4 = lane >> 4;
    #pragma unroll
    for (int nt = 0; nt < 4; ++nt){
        acc[nt][0] = bv.x; acc[nt][1] = bv.y; acc[nt][2] = bv.z; acc[nt][3] = bv.w;
    }
    #pragma unroll
    for (int ks = 0; ks < 4; ++ks){
        const int koff = ks*32 + hg4*8;
        #pragma unroll
        for (int nt = 0; nt < 4; ++nt){
            const int row = nt*16 + r16;
            const bf16x8 Bh = *(const bf16x8*)&Xh[row*XSTR + koff];   // 16B-aligned
            const bf16x8 Bl = *(const bf16x8*)&Xl[row*XSTR + koff];
            acc[nt] = __builtin_amdgcn_mfma_f32_16x16x32_bf16(Ah[ks], Bh, acc[nt], 0,0,0);
            acc[nt] = __builtin_amdgcn_mfma_f32_16x16x32_bf16(Ah[ks], Bl, acc[nt], 0,0,0);
            acc[nt] = __builtin_amdgcn_mfma_f32_16x16x32_bf16(Al[ks], Bh, acc[nt], 0,0,0);
        }
    }
}

__global__ __launch_bounds__(TPB, 4)
void k_mlp(const float* __restrict__ node1,
           const float* __restrict__ b2,
           const float* __restrict__ W3,
           float* __restrict__ out, int n)
{
    __shared__ unsigned short Xh[BROWS*XSTR];   // 17408 B
    __shared__ unsigned short Xl[BROWS*XSTR];   // 17408 B
    __shared__ float Ps[NWAVE][BROWS];          // 2 KB
    const int tid  = threadIdx.x;
    const int lane = tid & 63;
    const int w    = __builtin_amdgcn_readfirstlane(tid >> 6);
    const int hg4  = lane >> 4;
    const int r0   = blockIdx.x * BROWS;

    const bf16x8* wf = (const bf16x8*)g_wfrag;

    // ---- issue A1 frags (this wave's 16-feature slice) ----
    bf16x8 A1h[4], A1l[4];
    #pragma unroll
    for (int ks = 0; ks < 4; ++ks){
        A1h[ks] = wf[((0*4 + ks)*8 + w)*64 + lane];   // L=0,T=hi
        A1l[ks] = wf[((1*4 + ks)*8 + w)*64 + lane];   // L=0,T=lo
    }

    // ---- stage x: 64 rows x 32 f32x4 slots = 2048, 4 per thread, batched ----
    f32x4 xv[4];
    #pragma unroll
    for (int i = 0; i < 4; ++i){
        int idx = i*TPB + tid;            // = row*32 + kq
        int row = idx >> 5, kq = idx & 31;
        f32x4 v = {0.f, 0.f, 0.f, 0.f};
        if (r0 + row < n) v = reinterpret_cast<const f32x4*>(node1)[(size_t)(r0+row)*32 + kq];
        xv[i] = v;
    }
    #pragma unroll
    for (int i = 0; i < 4; ++i) asm volatile("" : "+v"(xv[i]));
    #pragma unroll
    for (int i = 0; i < 4; ++i){
        int idx = i*TPB + tid;
        int row = idx >> 5, kq = idx & 31;
        ushort4 hv, lv;
        split2(xv[i][0], hv.x, lv.x);
        split2(xv[i][1], hv.y, lv.y);
        split2(xv[i][2], hv.z, lv.z);
        split2(xv[i][3], hv.w, lv.w);
        *(ushort4*)&Xh[row*XSTR + kq*4] = hv;
        *(ushort4*)&Xl[row*XSTR + kq*4] = lv;
    }

    // pin A1 (fits: 32 regs)
    #pragma unroll
    for (int ks = 0; ks < 4; ++ks) asm volatile("" : "+v"(A1h[ks]), "+v"(A1l[ks]));
    __syncthreads();

    f32x4 acc[4];

    // ---- layer 1 ----
    {
        const float4 bv = *(const float4*)&g_b1p[w*16 + hg4*4];
        layer_compute(A1h, A1l, Xh, Xl, bv, acc, lane);
    }

    // ---- A2: issue + pin (A1 dead; 32 regs reused) ----
    bf16x8 A2h[4], A2l[4];
    #pragma unroll
    for (int ks = 0; ks < 4; ++ks){
        A2h[ks] = wf[((2*4 + ks)*8 + w)*64 + lane];   // L=1,T=hi
        A2l[ks] = wf[((3*4 + ks)*8 + w)*64 + lane];   // L=1,T=lo
    }
    #pragma unroll
    for (int ks = 0; ks < 4; ++ks) asm volatile("" : "+v"(A2h[ks]), "+v"(A2l[ks]));

    __syncthreads();   // everyone done READING X

    // relu + split writeback: lane holds features w*16+hg4*4..+3 of row nt*16+(lane&15)
    {
        const int r16 = lane & 15;
        const int c   = w*16 + hg4*4;
        #pragma unroll
        for (int nt = 0; nt < 4; ++nt){
            const int row = nt*16 + r16;
            ushort4 hv, lv; float v;
            v = fmaxf(acc[nt][0], 0.f); split2(v, hv.x, lv.x);
            v = fmaxf(acc[nt][1], 0.f); split2(v, hv.y, lv.y);
            v = fmaxf(acc[nt][2], 0.f); split2(v, hv.z, lv.z);
            v = fmaxf(acc[nt][3], 0.f); split2(v, hv.w, lv.w);
            *(ushort4*)&Xh[row*XSTR + c] = hv;   // 8B-aligned
            *(ushort4*)&Xl[row*XSTR + c] = lv;
        }
    }
    __syncthreads();   // h1 fully written

    // ---- layer 2 ----
    {
        const float4 bv = *(const float4*)&b2[w*16 + hg4*4];
        layer_compute(A2h, A2l, Xh, Xl, bv, acc, lane);
    }

    // ---- layer 3: lane partial over its 4 features, reduce across hg4 groups ----
    {
        const float4 wv = *(const float4*)&W3[w*16 + hg4*4];
        const int r16 = lane & 15;
        float p[4];
        #pragma unroll
        for (int nt = 0; nt < 4; ++nt){
            float q;
            q = fmaxf(acc[nt][0], 0.f) * wv.x;
            q = fmaf(fmaxf(acc[nt][1], 0.f), wv.y, q);
            q = fmaf(fmaxf(acc[nt][2], 0.f), wv.z, q);
            q = fmaf(fmaxf(acc[nt][3], 0.f), wv.w, q);
            q += __shfl_xor(q, 16);
            q += __shfl_xor(q, 32);
            p[nt] = q;
        }
        if (lane < 16){
            #pragma unroll
            for (int nt = 0; nt < 4; ++nt) Ps[w][nt*16 + r16] = p[nt];
        }
    }
    __syncthreads();

    // ---- cross-wave feature reduction + per-block softmax stats (wave 0) ----
    if (w == 0){
        const int ra = r0 + lane;
        const bool va = ra < n;
        float s = Ps[0][lane];
        #pragma unroll
        for (int ww = 1; ww < NWAVE; ++ww) s += Ps[ww][lane];
        if (va) out[ra] = s;
        float m = va ? s : -3.0e38f;
        #pragma unroll
        for (int off = 32; off > 0; off >>= 1) m = fmaxf(m, __shfl_xor(m, off));
        float e = va ? expf(s - m) : 0.f;
        #pragma unroll
        for (int off = 32; off > 0; off >>= 1) e += __shfl_xor(e, off);
        if (lane == 0){ g_pm[blockIdx.x] = m; g_ps[blockIdx.x] = e; }
    }
}

__global__ __launch_bounds__(1024)
void k_combine(int ng)
{
    __shared__ float red[17];
    const int tid = threadIdx.x, lane = tid & 63, wv = tid >> 6;

    float m = -3.0e38f;
    for (int i = tid; i < ng; i += 1024) m = fmaxf(m, g_pm[i]);
    #pragma unroll
    for (int off = 32; off > 0; off >>= 1) m = fmaxf(m, __shfl_xor(m, off));
    if (lane == 0) red[wv] = m;
    __syncthreads();
    if (tid < 64){
        float v = (lane < 16) ? red[lane] : -3.0e38f;
        #pragma unroll
        for (int off = 32; off > 0; off >>= 1) v = fmaxf(v, __shfl_xor(v, off));
        if (lane == 0) red[16] = v;
    }
    __syncthreads();
    m = red[16];

    float z = 0.f;
    for (int i = tid; i < ng; i += 1024) z += g_ps[i] * expf(g_pm[i] - m);
    #pragma unroll
    for (int off = 32; off > 0; off >>= 1) z += __shfl_xor(z, off);
    __syncthreads();
    if (lane == 0) red[wv] = z;
    __syncthreads();
    if (tid < 64){
        float v = (lane < 16) ? red[lane] : 0.f;
        #pragma unroll
        for (int off = 32; off > 0; off >>= 1) v += __shfl_xor(v, off);
        if (lane == 0){ g_m = m; g_invZ = 1.0f / v; }
    }
}

__global__ __launch_bounds__(256)
void k_norm(float* __restrict__ s, int n)
{
    const int i = blockIdx.x * 256 + threadIdx.x;
    const float m = g_m, r = g_invZ;
    const int n4 = n >> 2;
    if (i < n4){
        float4 v = reinterpret_cast<float4*>(s)[i];
        v.x = expf(v.x - m) * r;
        v.y = expf(v.y - m) * r;
        v.z = expf(v.z - m) * r;
        v.w = expf(v.w - m) * r;
        reinterpret_cast<float4*>(s)[i] = v;
    }
    const int rem = n - (n4 << 2);
    if (i < rem){
        int t = (n4 << 2) + i;
        s[t] = expf(s[t] - m) * r;
    }
}

extern "C" void kernel_launch(void* const* d_in, const int* in_sizes, int n_in,
                              void* d_out, int out_size, void* d_ws, size_t ws_size,
                              hipStream_t stream)
{
    const float* node1 = (const float*)d_in[0];
    const float* urep  = (const float*)d_in[1];
    const float* W1    = (const float*)d_in[3];
    const float* b1    = (const float*)d_in[4];
    const float* W2    = (const float*)d_in[5];
    const float* b2    = (const float*)d_in[6];
    const float* W3    = (const float*)d_in[7];
    float* out = (float*)d_out;

    const int n    = in_sizes[0] / DD;            // 200000
    const int nblk = (n + BROWS - 1) / BROWS;     // 3125

    k_prep<<<dim3(33), dim3(256), 0, stream>>>(W1, W2, b1, urep);
    k_mlp<<<dim3(nblk), dim3(TPB), 0, stream>>>(node1, b2, W3, out, n);
    k_combine<<<dim3(1), dim3(1024), 0, stream>>>(nblk);

    const int n4  = n >> 2;
    const int nb3 = (n4 + 255) / 256 > 0 ? (n4 + 255) / 256 : 1;
    k_norm<<<dim3(nb3), dim3(256), 0, stream>>>(out, n);
}